// Round 16
// baseline (89.185 us; speedup 1.0000x reference)
//
#include <hip/hip_runtime.h>

// CRF loss, S=512, B=256, L=128; out = sum_b log_z_b - gold.
//
// R16 = R15 associative chunked scan (verified absmax 0.0) with:
//  - bf16 LDS staging (32 KB tile, 16B-granule XOR swizzle c16^(b&7)) ->
//    __launch_bounds__(256,4): 4 blocks/CU, whole 1024-block grid resident,
//    2x staging waves in flight vs R15's 64KB/2-block config.
//  - gold merged into the dots kernel (one fewer launch; gather latency
//    overlaps dots' loads).
//
// Math (R13-verified): 64 chunks of NT=8; chunk product P_c rank-1 to
// ~0.42^6: P_c ~ x_c y_c^T/(1^T x_c); y fwd chain from ones, x bwd chain.
//   log2 Z_b = log2(v0.x^_0) - log2(1^T x^_0)
//            + sum_{c>=1} [log2(y^_{c-1}.x^_c) - log2(1^T x^_c) + Ly_{c-1}]
//            + log2(1^T y^_63) + Ly_63      (x-scales cancel per ratio).
// Chain step (R9-proven): 8x mfma_scale_f32_16x16x128_f8f6f4, state bf8 e5m2,
// A e4m3, scale byte sb=(250|248)-e(shfl(ac00,b)) via MFMA B-scale (e8m0),
// L += 127-sb exact. Layouts verified R5-R15.
//
// Fallback (small ws): R7-proven bf16 in-register full scan.

#define LOG2E 1.4426950408889634f
#define LN2F  0.6931471805599453f

typedef float        f32x4  __attribute__((ext_vector_type(4)));
typedef int          i32x8  __attribute__((ext_vector_type(8)));
typedef unsigned int u32x4  __attribute__((ext_vector_type(4)));
typedef short        bf16x8 __attribute__((ext_vector_type(8)));
typedef __bf16       bf16x2 __attribute__((ext_vector_type(2)));

__device__ __forceinline__ unsigned packbf2(float lo, float hi) {
    bf16x2 p = { (__bf16)lo, (__bf16)hi };
    return __builtin_bit_cast(unsigned, p);
}
__device__ __forceinline__ float bflo(unsigned w) { return __uint_as_float(w << 16); }
__device__ __forceinline__ float bfhi(unsigned w) { return __uint_as_float(w & 0xFFFF0000u); }

#define MFMAX(Aop, Bop, SCL) \
    __builtin_amdgcn_mfma_scale_f32_16x16x128_f8f6f4( \
        Aop, Bop, zero4, 0, 1, 0, 0x7F7F7F7F, 0, SCL)

// ================= setup: A fragments -> Afrbuf[2][8][64] i32x8 ==========
__global__ __launch_bounds__(64) void crf_setup_kernel(
    const float* __restrict__ Tm, int* __restrict__ Afrbuf)
{
    const int dir = blockIdx.x >> 3;
    const int jt  = blockIdx.x & 7;
    const int l   = threadIdx.x;
    const int b   = l & 15;
    const int g   = l >> 4;
    i32x8 af;
#pragma unroll
    for (int d = 0; d < 8; ++d) {
        float a0, a1, a2, a3;
        if (!dir) {   // fwd: A[j][k~] = E[16d+4g+c][16jt+b]
            const int rb = 16 * d + 4 * g, col = 16 * jt + b;
            a0 = __builtin_amdgcn_exp2f(Tm[(rb + 0) * 128 + col] * LOG2E);
            a1 = __builtin_amdgcn_exp2f(Tm[(rb + 1) * 128 + col] * LOG2E);
            a2 = __builtin_amdgcn_exp2f(Tm[(rb + 2) * 128 + col] * LOG2E);
            a3 = __builtin_amdgcn_exp2f(Tm[(rb + 3) * 128 + col] * LOG2E);
        } else {      // bwd: A2[i][k~] = E[16jt+b][16d+4g+c]
            const int row = 16 * jt + b, cb = 16 * d + 4 * g;
            a0 = __builtin_amdgcn_exp2f(Tm[row * 128 + cb + 0] * LOG2E);
            a1 = __builtin_amdgcn_exp2f(Tm[row * 128 + cb + 1] * LOG2E);
            a2 = __builtin_amdgcn_exp2f(Tm[row * 128 + cb + 2] * LOG2E);
            a3 = __builtin_amdgcn_exp2f(Tm[row * 128 + cb + 3] * LOG2E);
        }
        int w = __builtin_amdgcn_cvt_pk_fp8_f32(a0, a1, 0, false);
        af[d] = __builtin_amdgcn_cvt_pk_fp8_f32(a2, a3, w, true);
    }
    *(i32x8*)&Afrbuf[((size_t)blockIdx.x * 64 + l) * 8] = af;
}

// ================= chunk kernel: 1024 blocks x 256 thr ====================
// bi: chunk = bi>>4 (0..63), gb = bi&15. Both dirs per block.
__global__ __launch_bounds__(256, 4) void crf_chunk_kernel(
    const float* __restrict__ emit,   // (512,256,128)
    const int*   __restrict__ Afrbuf, // [2][8][64] i32x8
    float* __restrict__ yx,           // [256 bg][2 dir][64 chunk][128]
    int*   __restrict__ Ls)           // [256 bg][2 dir][64 chunk]
{
    const int bi    = blockIdx.x;
    const int chunk = bi >> 4;
    const int gb    = bi & 15;
    const int tid   = threadIdx.x;
    const int NT    = (chunk == 63) ? 7 : 8;
    const int t0    = 1 + 8 * chunk;

    // bf16 tile: [8 k][16 bb][128 j], rows of 128 ushorts = 16 chunks of 16B,
    // chunk16 stored at c16 ^ (bb&7).
    __shared__ __align__(16) unsigned short xt[16384];   // 32 KiB

    // ---- stage exp(emit tile) as bf16, swizzled ----
#pragma unroll
    for (int i = 0; i < 8; ++i) {
        const int lin = i * 256 + tid;      // 16B-chunk linear id 0..2047
        const int r   = lin >> 4;           // row 0..127 = k*16 + bb
        const int c16 = lin & 15;
        const int k   = r >> 4;
        const int bb  = r & 15;
        int t = t0 + k; if (t > 511) t = 511;
        const float4* gp = (const float4*)(emit + (size_t)t * 32768
                                           + (gb * 16 + bb) * 128 + 8 * c16);
        const float4 e0 = gp[0], e1 = gp[1];
        u32x4 o;
        o[0] = packbf2(__builtin_amdgcn_exp2f(e0.x * LOG2E),
                       __builtin_amdgcn_exp2f(e0.y * LOG2E));
        o[1] = packbf2(__builtin_amdgcn_exp2f(e0.z * LOG2E),
                       __builtin_amdgcn_exp2f(e0.w * LOG2E));
        o[2] = packbf2(__builtin_amdgcn_exp2f(e1.x * LOG2E),
                       __builtin_amdgcn_exp2f(e1.y * LOG2E));
        o[3] = packbf2(__builtin_amdgcn_exp2f(e1.z * LOG2E),
                       __builtin_amdgcn_exp2f(e1.w * LOG2E));
        *(u32x4*)&xt[r * 128 + ((c16 ^ (bb & 7)) << 3)] = o;
    }
    __syncthreads();

    const int wv = tid >> 6;
    if (wv >= 2) return;                 // staging-only waves exit

    const int dir = wv;
    const int l   = tid & 63;
    const int b   = l & 15;
    const int g   = l >> 4;
    const int bg  = gb * 16 + b;
    const int bsw = b & 7;
    const f32x4 zero4 = {0.f, 0.f, 0.f, 0.f};

    // ---- A fragments: 8 coalesced 32B loads ----
    i32x8 Afr[8];
#pragma unroll
    for (int jt = 0; jt < 8; ++jt)
        Afr[jt] = *(const i32x8*)&Afrbuf[(((size_t)dir * 8 + jt) * 64 + l) * 8];

    // ---- init state ----
    i32x8 Bq;
    f32x4 u[8];
    int L, sclw;
    if (!dir) {
        int one2 = __builtin_amdgcn_cvt_pk_bf8_f32(1.f, 1.f, 0, false);
        one2 = __builtin_amdgcn_cvt_pk_bf8_f32(1.f, 1.f, one2, true);
#pragma unroll
        for (int d = 0; d < 8; ++d) Bq[d] = one2;
        L = 4;  sclw = 123 * 0x01010101;      // sigma = -4
    } else {
#pragma unroll
        for (int d = 0; d < 8; ++d) u[d] = (f32x4){1.f, 1.f, 1.f, 1.f};
        L = 8;  sclw = 119 * 0x01010101;      // sigma = -8 (extra margin)
    }

    const size_t obase = ((size_t)(bg * 2 + dir) * 64 + chunk) * 128;

#pragma unroll
    for (int k = 0; k < 8; ++k) {
        if (k < NT) {
            const int krow = dir ? (NT - 1 - k) : k;
            f32x4 xv[8];
#pragma unroll
            for (int jt = 0; jt < 8; ++jt) {
                const int c16r = 2 * jt + (g >> 1);
                const uint2 uu = *(const uint2*)&xt[(krow * 16 + b) * 128
                    + ((c16r ^ bsw) << 3) + (g & 1) * 4];
                xv[jt][0] = bflo(uu.x); xv[jt][1] = bfhi(uu.x);
                xv[jt][2] = bflo(uu.y); xv[jt][3] = bfhi(uu.y);
            }
            if (dir) {   // bwd: w = x .* u -> B operand
#pragma unroll
                for (int d = 0; d < 8; ++d) {
                    f32x4 w = xv[d] * u[d];
                    int bw = __builtin_amdgcn_cvt_pk_bf8_f32(w[0], w[1], 0, false);
                    Bq[d]  = __builtin_amdgcn_cvt_pk_bf8_f32(w[2], w[3], bw, true);
                }
            }
            f32x4 ac[8];
#pragma unroll
            for (int jt = 0; jt < 8; ++jt)
                ac[jt] = MFMAX(Afr[jt], Bq, sclw);
            float a00 = __shfl(ac[0][0], b);
            int ea = (__float_as_int(a00) >> 23) & 0xFF;
            int sb = (dir ? 248 : 250) - ea;
            sb = sb < 1 ? 1 : (sb > 254 ? 254 : sb);
            const bool last = (k == NT - 1);
            if (!last) { L += 127 - sb; sclw = sb * 0x01010101; }
            if (!dir) {
#pragma unroll
                for (int jt = 0; jt < 8; ++jt) {
                    f32x4 vv = ac[jt] * xv[jt];
                    if (last) *(f32x4*)&yx[obase + 16 * jt + 4 * g] = vv;
                    else {
                        int bw = __builtin_amdgcn_cvt_pk_bf8_f32(vv[0], vv[1], 0, false);
                        Bq[jt] = __builtin_amdgcn_cvt_pk_bf8_f32(vv[2], vv[3], bw, true);
                    }
                }
            } else {
#pragma unroll
                for (int jt = 0; jt < 8; ++jt) {
                    u[jt] = ac[jt];
                    if (last) *(f32x4*)&yx[obase + 16 * jt + 4 * g] = ac[jt];
                }
            }
        }
    }
    if (l < 16)
        Ls[((gb * 16 + l) * 2 + dir) * 64 + chunk] = L;
}

// ========== dots+gold: 256 blocks (batch) x 256 thr (4 waves) =============
// diff_part[b] = log_z_b - gold_b.
__global__ __launch_bounds__(256) void crf_dotsgold_kernel(
    const float* __restrict__ emit, const float* __restrict__ yx,
    const int* __restrict__ Ls, const float* __restrict__ Tm,
    const int* __restrict__ labels, const int* __restrict__ startp,
    float* __restrict__ diff_part)
{
    const int b   = blockIdx.x;
    const int tid = threadIdx.x;
    const int w   = tid >> 6;
    const int l   = tid & 63;
    __shared__ int lab[512];
    __shared__ float rg[4], rd[4];

    lab[tid]       = labels[b * 512 + tid];
    lab[tid + 256] = labels[b * 512 + tid + 256];
    __syncthreads();

    // ---- gold partial (thread handles t = tid, t = tid+256) ----
    float s = 0.f;
    {
        int y0 = lab[tid];
        int p0 = (tid == 0) ? startp[0] : lab[tid - 1];
        s += emit[((size_t)tid * 256 + b) * 128 + y0] + Tm[p0 * 128 + y0];
        int t1 = tid + 256;
        int y1 = lab[t1];
        int p1 = lab[t1 - 1];
        s += emit[((size_t)t1 * 256 + b) * 128 + y1] + Tm[p1 * 128 + y1];
    }
#pragma unroll
    for (int off = 1; off < 64; off <<= 1) s += __shfl_xor(s, off);
    if (l == 0) rg[w] = s;

    // ---- dots terms (c = w, w+4, ...) ----
    const float* yb  = yx + (size_t)(b * 2) * 64 * 128;        // [0][c][j]
    const float* xb  = yb + 64 * 128;                          // [1][c][j]
    const int*   Lyb = Ls + b * 2 * 64;                        // [0][c]

    float acc = 0.f;
#pragma unroll 1
    for (int c = w; c <= 64; c += 4) {
        float term;
        if (c == 64) {
            const float* yp = yb + 63 * 128;
            float s2 = yp[l] + yp[64 + l];
#pragma unroll
            for (int off = 1; off < 64; off <<= 1) s2 += __shfl_xor(s2, off);
            term = __log2f(s2) + (float)Lyb[63];
        } else {
            float pa, pb;
            if (c == 0) {
                pa = __builtin_amdgcn_exp2f(emit[b * 128 + l] * LOG2E);
                pb = __builtin_amdgcn_exp2f(emit[b * 128 + 64 + l] * LOG2E);
            } else {
                const float* yp = yb + (c - 1) * 128;
                pa = yp[l]; pb = yp[64 + l];
            }
            const float* xp = xb + c * 128;
            float xa = xp[l], xb2 = xp[64 + l];
            float sp = pa * xa + pb * xb2;
            float tp = xa + xb2;
#pragma unroll
            for (int off = 1; off < 64; off <<= 1) {
                sp += __shfl_xor(sp, off);
                tp += __shfl_xor(tp, off);
            }
            term = __log2f(sp) - __log2f(tp)
                 + (c ? (float)Lyb[c - 1] : 0.f);
        }
        acc += term;
    }
    if (l == 0) rd[w] = acc;
    __syncthreads();
    if (tid == 0) {
        float lz   = ((rd[0] + rd[1]) + (rd[2] + rd[3])) * LN2F;
        float gold = (rg[0] + rg[1]) + (rg[2] + rg[3]);
        diff_part[b] = lz - gold;
    }
}

// final (fast path): sum 256 diffs.
__global__ __launch_bounds__(256) void crf_sum_kernel(
    const float* __restrict__ diff_part, float* __restrict__ out)
{
    const int tid = threadIdx.x;
    __shared__ float r[4];
    float v = diff_part[tid];
#pragma unroll
    for (int off = 1; off < 64; off <<= 1) v += __shfl_xor(v, off);
    if ((tid & 63) == 0) r[tid >> 6] = v;
    __syncthreads();
    if (tid == 0) out[0] = (r[0] + r[1]) + (r[2] + r[3]);
}

// ================= bf16 fallback full scan (R7, proven) =================
#define MFMAB(Aop, Bop, Cop) \
    __builtin_amdgcn_mfma_f32_16x16x32_bf16( \
        __builtin_bit_cast(bf16x8, Aop), __builtin_bit_cast(bf16x8, Bop), Cop, 0, 0, 0)

#define STEPB(SLOT, TPF, DOPF, RN, LAST) do {                                 \
    f32x4 ac[8];                                                              \
    _Pragma("unroll") for (int jt = 0; jt < 8; ++jt)                          \
        ac[jt] = MFMAB(Afr[0][jt], Bf[0], zero4);                             \
    _Pragma("unroll") for (int ch = 1; ch < 4; ++ch)                          \
        _Pragma("unroll") for (int jt = 0; jt < 8; ++jt)                      \
            ac[jt] = MFMAB(Afr[ch][jt], Bf[ch], ac[jt]);                      \
    float xv[8][4];                                                           \
    _Pragma("unroll") for (int jt = 0; jt < 8; ++jt) {                        \
        float4 xw = xbf[SLOT][jt];                                            \
        xv[jt][0] = __builtin_amdgcn_exp2f(xw.x * LOG2E);                     \
        xv[jt][1] = __builtin_amdgcn_exp2f(xw.y * LOG2E);                     \
        xv[jt][2] = __builtin_amdgcn_exp2f(xw.z * LOG2E);                     \
        xv[jt][3] = __builtin_amdgcn_exp2f(xw.w * LOG2E);                     \
    }                                                                         \
    if (DOPF) {                                                               \
        int tp = (TPF); if (tp > 511) tp = 511;                               \
        _Pragma("unroll") for (int jt = 0; jt < 8; ++jt)                      \
            xbf[SLOT][jt] = emf4[8192 * tp + lb + 4 * jt];                    \
    }                                                                         \
    float vv[8][4];                                                           \
    _Pragma("unroll") for (int jt = 0; jt < 8; ++jt)                          \
        _Pragma("unroll") for (int r = 0; r < 4; ++r)                         \
            vv[jt][r] = ac[jt][r] * xv[jt][r];                                \
    if (RN) {                                                                 \
        float mx = vv[0][0];                                                  \
        _Pragma("unroll") for (int jt = 0; jt < 8; ++jt)                      \
            _Pragma("unroll") for (int r = 0; r < 4; ++r)                     \
                mx = fmaxf(mx, vv[jt][r]);                                    \
        mx = fmaxf(mx, __shfl_xor(mx, 16));                                   \
        mx = fmaxf(mx, __shfl_xor(mx, 32));                                   \
        int Ee = (__float_as_int(mx) >> 23) & 0xFF;                           \
        if (Ee > 254) Ee = 254;                                               \
        ls2 += Ee - 127;                                                      \
        float scl = __int_as_float((254 - Ee) << 23);                         \
        _Pragma("unroll") for (int jt = 0; jt < 8; ++jt)                      \
            _Pragma("unroll") for (int r = 0; r < 4; ++r)                     \
                vv[jt][r] *= scl;                                             \
    }                                                                         \
    if (LAST) {                                                               \
        fin = 0.f;                                                            \
        _Pragma("unroll") for (int jt = 0; jt < 8; ++jt)                      \
            fin += (vv[jt][0] + vv[jt][1]) + (vv[jt][2] + vv[jt][3]);         \
    } else {                                                                  \
        _Pragma("unroll") for (int ch = 0; ch < 4; ++ch) {                    \
            Bf[ch][0] = packbf2(vv[2*ch][0],     vv[2*ch][1]);                \
            Bf[ch][1] = packbf2(vv[2*ch][2],     vv[2*ch][3]);                \
            Bf[ch][2] = packbf2(vv[2*ch + 1][0], vv[2*ch + 1][1]);            \
            Bf[ch][3] = packbf2(vv[2*ch + 1][2], vv[2*ch + 1][3]);            \
        }                                                                     \
    }                                                                         \
} while (0)

__global__ __launch_bounds__(64, 1) void crf_scan_bf16_kernel(
    const float* __restrict__ emit,
    const float* __restrict__ Tm,
    float* __restrict__ scan_part)
{
    const int gb = blockIdx.x;
    const int l  = threadIdx.x;
    const int b  = l & 15;
    const int g  = l >> 4;
    const int bg = gb * 16 + b;
    const int lb = 32 * bg + g;

    const float4* emf4 = (const float4*)emit;
    const f32x4 zero4 = {0.f, 0.f, 0.f, 0.f};

    u32x4 Afr[4][8];
#pragma unroll
    for (int ch = 0; ch < 4; ++ch)
#pragma unroll
        for (int p = 0; p < 4; ++p) {
            const int e0 = 2 * p, e1 = 2 * p + 1;
            const int jp0 = 32 * ch + 16 * (e0 >> 2) + 4 * g + (e0 & 3);
            const int jp1 = 32 * ch + 16 * (e1 >> 2) + 4 * g + (e1 & 3);
#pragma unroll
            for (int jt = 0; jt < 8; ++jt) {
                float a0 = __builtin_amdgcn_exp2f(Tm[jp0 * 128 + 16 * jt + b] * LOG2E);
                float a1 = __builtin_amdgcn_exp2f(Tm[jp1 * 128 + 16 * jt + b] * LOG2E);
                Afr[ch][jt][p] = packbf2(a0, a1);
            }
        }

    u32x4 Bf[4];
    {
        float x0[8][4];
#pragma unroll
        for (int jt = 0; jt < 8; ++jt) {
            float4 e = emf4[lb + 4 * jt];
            x0[jt][0] = __builtin_amdgcn_exp2f(e.x * LOG2E);
            x0[jt][1] = __builtin_amdgcn_exp2f(e.y * LOG2E);
            x0[jt][2] = __builtin_amdgcn_exp2f(e.z * LOG2E);
            x0[jt][3] = __builtin_amdgcn_exp2f(e.w * LOG2E);
        }
#pragma unroll
        for (int ch = 0; ch < 4; ++ch) {
            Bf[ch][0] = packbf2(x0[2 * ch][0],     x0[2 * ch][1]);
            Bf[ch][1] = packbf2(x0[2 * ch][2],     x0[2 * ch][3]);
            Bf[ch][2] = packbf2(x0[2 * ch + 1][0], x0[2 * ch + 1][1]);
            Bf[ch][3] = packbf2(x0[2 * ch + 1][2], x0[2 * ch + 1][3]);
        }
    }

    float4 xbf[4][8];
#pragma unroll
    for (int k = 0; k < 4; ++k)
#pragma unroll
        for (int jt = 0; jt < 8; ++jt)
            xbf[k][jt] = emf4[8192 * (1 + k) + lb + 4 * jt];

    int ls2 = 0;
    float fin = 0.f;

#pragma unroll 1
    for (int grp = 0; grp < 63; ++grp) {
        const int t0 = 1 + 8 * grp;
        STEPB(0, t0 + 4,  1, 0, 0);
        STEPB(1, t0 + 5,  1, 0, 0);
        STEPB(2, t0 + 6,  1, 0, 0);
        STEPB(3, t0 + 7,  1, 0, 0);
        STEPB(0, t0 + 8,  1, 0, 0);
        STEPB(1, t0 + 9,  1, 0, 0);
        STEPB(2, t0 + 10, 1, 0, 0);
        STEPB(3, t0 + 11, 1, 1, 0);
    }
    STEPB(0, 509, 1, 0, 0);
    STEPB(1, 510, 1, 0, 0);
    STEPB(2, 511, 1, 0, 0);
    STEPB(3, 0,   0, 0, 0);
    STEPB(0, 0,   0, 0, 0);
    STEPB(1, 0,   0, 0, 0);
    STEPB(2, 0,   0, 0, 1);

    fin += __shfl_xor(fin, 16);
    fin += __shfl_xor(fin, 32);
    if (l < 16)
        scan_part[gb * 16 + l] = ((float)ls2 + __log2f(fin)) * LN2F;
}

// ================= gold + final (fallback path) =================
__global__ __launch_bounds__(256) void crf_gold_kernel(
    const float* __restrict__ emit, const float* __restrict__ Tm,
    const int* __restrict__ labels, const int* __restrict__ startp,
    float* __restrict__ gold_part)
{
    const int b = blockIdx.x, tid = threadIdx.x;
    __shared__ int lab[512];
    __shared__ float r[4];
    lab[tid]       = labels[b * 512 + tid];
    lab[tid + 256] = labels[b * 512 + tid + 256];
    __syncthreads();
    float s = 0.f;
    {
        int y0 = lab[tid];
        int p0 = (tid == 0) ? startp[0] : lab[tid - 1];
        s += emit[((size_t)tid * 256 + b) * 128 + y0] + Tm[p0 * 128 + y0];
        int t1 = tid + 256;
        int y1 = lab[t1];
        int p1 = lab[t1 - 1];
        s += emit[((size_t)t1 * 256 + b) * 128 + y1] + Tm[p1 * 128 + y1];
    }
#pragma unroll
    for (int off = 1; off < 64; off <<= 1) s += __shfl_xor(s, off);
    if ((tid & 63) == 0) r[tid >> 6] = s;
    __syncthreads();
    if (tid == 0) gold_part[b] = (r[0] + r[1]) + (r[2] + r[3]);
}

__global__ __launch_bounds__(256) void crf_final_kernel(
    const float* __restrict__ scan_part, const float* __restrict__ gold_part,
    float* __restrict__ out)
{
    const int tid = threadIdx.x;
    __shared__ float r[4];
    float v = scan_part[tid] - gold_part[tid];
#pragma unroll
    for (int off = 1; off < 64; off <<= 1) v += __shfl_xor(v, off);
    if ((tid & 63) == 0) r[tid >> 6] = v;
    __syncthreads();
    if (tid == 0) out[0] = (r[0] + r[1]) + (r[2] + r[3]);
}

extern "C" void kernel_launch(void* const* d_in, const int* in_sizes, int n_in,
                              void* d_out, int out_size, void* d_ws, size_t ws_size,
                              hipStream_t stream) {
    const float* emit   = (const float*)d_in[0];
    const float* Tm     = (const float*)d_in[1];
    const int*   labels = (const int*)d_in[2];
    const int*   startp = (const int*)d_in[3];

    const size_t af_bytes = (size_t)2 * 8 * 64 * 32;          // 32,768
    const size_t yx_bytes = (size_t)256 * 2 * 64 * 128 * 4;   // 16,777,216
    const size_t Ls_bytes = (size_t)256 * 2 * 64 * 4;         // 131,072

    if (ws_size >= af_bytes + yx_bytes + Ls_bytes + 4096) {
        int*   Afrbuf    = (int*)d_ws;
        float* yx        = (float*)((char*)d_ws + af_bytes);
        int*   Ls        = (int*)((char*)d_ws + af_bytes + yx_bytes);
        float* diff_part = (float*)((char*)d_ws + af_bytes + yx_bytes + Ls_bytes);
        crf_setup_kernel   <<<16,   64, 0, stream>>>(Tm, Afrbuf);
        crf_chunk_kernel   <<<1024, 256, 0, stream>>>(emit, Afrbuf, yx, Ls);
        crf_dotsgold_kernel<<<256,  256, 0, stream>>>(emit, yx, Ls, Tm, labels,
                                                      startp, diff_part);
        crf_sum_kernel     <<<1,    256, 0, stream>>>(diff_part, (float*)d_out);
    } else {
        float* scan_part = (float*)d_ws;
        float* gold_part = scan_part + 256;
        crf_scan_bf16_kernel<<<16, 64, 0, stream>>>(emit, Tm, scan_part);
        crf_gold_kernel<<<256, 256, 0, stream>>>(emit, Tm, labels, startp, gold_part);
        crf_final_kernel<<<1, 256, 0, stream>>>(scan_part, gold_part, (float*)d_out);
    }
}

// Round 17
// 50.515 us; speedup vs baseline: 1.7655x; 1.7655x over previous
//
#include <hip/hip_runtime.h>

// CRF loss, S=512, B=256, L=128; out = sum_b log_z_b - gold.
//
// R17 = R15's EXACT chunk kernel (proven 52.2us total, absmax 0.0:
// f32 64KB LDS tile, 2 blocks/CU, single emit pass, both dirs per block)
// + R16's verified gold-merge into the dots kernel (one fewer launch).
// R16's bf16/4-block experiment REVERTED: it amplified HBM traffic
// (FETCH 144MB/2.15x, WRITE 56MB/3.3x — concurrent scattered-write
// working set quadrupled -> L2 partial-line RMW thrash).
//
// Math (R13-verified): 64 chunks of NT=8; chunk product P_c rank-1 to
// ~0.42^6: P_c ~ x_c y_c^T/(1^T x_c); y fwd chain from ones, x bwd chain.
//   log2 Z_b = log2(v0.x^_0) - log2(1^T x^_0)
//            + sum_{c>=1} [log2(y^_{c-1}.x^_c) - log2(1^T x^_c) + Ly_{c-1}]
//            + log2(1^T y^_63) + Ly_63      (x-scales cancel per ratio).
// Chain step (R9-proven): 8x mfma_scale_f32_16x16x128_f8f6f4, state bf8 e5m2,
// A e4m3, scale byte sb=(250|248)-e(shfl(ac00,b)) via MFMA B-scale (e8m0),
// L += 127-sb exact. Layouts verified R5-R16.
//
// Fallback (small ws): R7-proven bf16 in-register full scan.

#define LOG2E 1.4426950408889634f
#define LN2F  0.6931471805599453f

typedef float        f32x4  __attribute__((ext_vector_type(4)));
typedef int          i32x8  __attribute__((ext_vector_type(8)));
typedef unsigned int u32x4  __attribute__((ext_vector_type(4)));
typedef short        bf16x8 __attribute__((ext_vector_type(8)));
typedef __bf16       bf16x2 __attribute__((ext_vector_type(2)));

__device__ __forceinline__ unsigned packbf2(float lo, float hi) {
    bf16x2 p = { (__bf16)lo, (__bf16)hi };
    return __builtin_bit_cast(unsigned, p);
}

#define MFMAX(Aop, Bop, SCL) \
    __builtin_amdgcn_mfma_scale_f32_16x16x128_f8f6f4( \
        Aop, Bop, zero4, 0, 1, 0, 0x7F7F7F7F, 0, SCL)

// ================= setup: A fragments -> Afrbuf[2][8][64] i32x8 ==========
__global__ __launch_bounds__(64) void crf_setup_kernel(
    const float* __restrict__ Tm, int* __restrict__ Afrbuf)
{
    const int dir = blockIdx.x >> 3;
    const int jt  = blockIdx.x & 7;
    const int l   = threadIdx.x;
    const int b   = l & 15;
    const int g   = l >> 4;
    i32x8 af;
#pragma unroll
    for (int d = 0; d < 8; ++d) {
        float a0, a1, a2, a3;
        if (!dir) {   // fwd: A[j][k~] = E[16d+4g+c][16jt+b]
            const int rb = 16 * d + 4 * g, col = 16 * jt + b;
            a0 = __builtin_amdgcn_exp2f(Tm[(rb + 0) * 128 + col] * LOG2E);
            a1 = __builtin_amdgcn_exp2f(Tm[(rb + 1) * 128 + col] * LOG2E);
            a2 = __builtin_amdgcn_exp2f(Tm[(rb + 2) * 128 + col] * LOG2E);
            a3 = __builtin_amdgcn_exp2f(Tm[(rb + 3) * 128 + col] * LOG2E);
        } else {      // bwd: A2[i][k~] = E[16jt+b][16d+4g+c]
            const int row = 16 * jt + b, cb = 16 * d + 4 * g;
            a0 = __builtin_amdgcn_exp2f(Tm[row * 128 + cb + 0] * LOG2E);
            a1 = __builtin_amdgcn_exp2f(Tm[row * 128 + cb + 1] * LOG2E);
            a2 = __builtin_amdgcn_exp2f(Tm[row * 128 + cb + 2] * LOG2E);
            a3 = __builtin_amdgcn_exp2f(Tm[row * 128 + cb + 3] * LOG2E);
        }
        int w = __builtin_amdgcn_cvt_pk_fp8_f32(a0, a1, 0, false);
        af[d] = __builtin_amdgcn_cvt_pk_fp8_f32(a2, a3, w, true);
    }
    *(i32x8*)&Afrbuf[((size_t)blockIdx.x * 64 + l) * 8] = af;
}

// ================= chunk kernel: 1024 blocks x 256 thr (R15 exact) ========
// bi: chunk = bi>>4 (0..63), gb = bi&15. Both dirs per block.
__global__ __launch_bounds__(256, 2) void crf_chunk_kernel(
    const float* __restrict__ emit,   // (512,256,128)
    const int*   __restrict__ Afrbuf, // [2][8][64] i32x8
    float* __restrict__ yx,           // [256 bg][2 dir][64 chunk][128]
    int*   __restrict__ Ls)           // [256 bg][2 dir][64 chunk]
{
    const int bi    = blockIdx.x;
    const int chunk = bi >> 4;
    const int gb    = bi & 15;
    const int tid   = threadIdx.x;
    const int NT    = (chunk == 63) ? 7 : 8;
    const int t0    = 1 + 8 * chunk;

    __shared__ __align__(16) float xt[16384];   // [8 k][16 bb][128 j] swizzled

    // ---- stage exp(emit tile) into LDS, XOR-swizzled ----
#pragma unroll
    for (int i = 0; i < 16; ++i) {
        const int f4 = i * 256 + tid;
        const int r  = f4 >> 5;          // 0..127 = k*16 + bb
        const int c  = f4 & 31;          // 16B chunk within row
        const int k  = r >> 4;
        const int bb = r & 15;
        int t = t0 + k; if (t > 511) t = 511;
        const float4 e = *(const float4*)(emit
            + (size_t)t * 32768 + (gb * 16 + bb) * 128 + 4 * c);
        f32x4 o;
        o[0] = __builtin_amdgcn_exp2f(e.x * LOG2E);
        o[1] = __builtin_amdgcn_exp2f(e.y * LOG2E);
        o[2] = __builtin_amdgcn_exp2f(e.z * LOG2E);
        o[3] = __builtin_amdgcn_exp2f(e.w * LOG2E);
        *(f32x4*)&xt[r * 128 + 4 * (c ^ (bb & 7))] = o;
    }
    __syncthreads();

    const int wv = tid >> 6;
    if (wv >= 2) return;                 // staging-only waves exit

    const int dir = wv;
    const int l   = tid & 63;
    const int b   = l & 15;
    const int g   = l >> 4;
    const int bg  = gb * 16 + b;
    const int bsw = b & 7;
    const f32x4 zero4 = {0.f, 0.f, 0.f, 0.f};

    // ---- A fragments: 8 coalesced 32B loads ----
    i32x8 Afr[8];
#pragma unroll
    for (int jt = 0; jt < 8; ++jt)
        Afr[jt] = *(const i32x8*)&Afrbuf[(((size_t)dir * 8 + jt) * 64 + l) * 8];

    // ---- init state ----
    i32x8 Bq;
    f32x4 u[8];
    int L, sclw;
    if (!dir) {
        int one2 = __builtin_amdgcn_cvt_pk_bf8_f32(1.f, 1.f, 0, false);
        one2 = __builtin_amdgcn_cvt_pk_bf8_f32(1.f, 1.f, one2, true);
#pragma unroll
        for (int d = 0; d < 8; ++d) Bq[d] = one2;
        L = 4;  sclw = 123 * 0x01010101;      // sigma = -4
    } else {
#pragma unroll
        for (int d = 0; d < 8; ++d) u[d] = (f32x4){1.f, 1.f, 1.f, 1.f};
        L = 8;  sclw = 119 * 0x01010101;      // sigma = -8 (extra margin)
    }

    const size_t obase = ((size_t)(bg * 2 + dir) * 64 + chunk) * 128;

#pragma unroll
    for (int k = 0; k < 8; ++k) {
        if (k < NT) {
            const int krow = dir ? (NT - 1 - k) : k;
            f32x4 xv[8];
#pragma unroll
            for (int jt = 0; jt < 8; ++jt)
                xv[jt] = *(const f32x4*)&xt[(krow * 16 + b) * 128
                                            + 4 * ((4 * jt + g) ^ bsw)];
            if (dir) {   // bwd: w = x .* u -> B operand
#pragma unroll
                for (int d = 0; d < 8; ++d) {
                    f32x4 w = xv[d] * u[d];
                    int bw = __builtin_amdgcn_cvt_pk_bf8_f32(w[0], w[1], 0, false);
                    Bq[d]  = __builtin_amdgcn_cvt_pk_bf8_f32(w[2], w[3], bw, true);
                }
            }
            f32x4 ac[8];
#pragma unroll
            for (int jt = 0; jt < 8; ++jt)
                ac[jt] = MFMAX(Afr[jt], Bq, sclw);
            float a00 = __shfl(ac[0][0], b);
            int ea = (__float_as_int(a00) >> 23) & 0xFF;
            int sb = (dir ? 248 : 250) - ea;
            sb = sb < 1 ? 1 : (sb > 254 ? 254 : sb);
            const bool last = (k == NT - 1);
            if (!last) { L += 127 - sb; sclw = sb * 0x01010101; }
            if (!dir) {
#pragma unroll
                for (int jt = 0; jt < 8; ++jt) {
                    f32x4 vv = ac[jt] * xv[jt];
                    if (last) *(f32x4*)&yx[obase + 16 * jt + 4 * g] = vv;
                    else {
                        int bw = __builtin_amdgcn_cvt_pk_bf8_f32(vv[0], vv[1], 0, false);
                        Bq[jt] = __builtin_amdgcn_cvt_pk_bf8_f32(vv[2], vv[3], bw, true);
                    }
                }
            } else {
#pragma unroll
                for (int jt = 0; jt < 8; ++jt) {
                    u[jt] = ac[jt];
                    if (last) *(f32x4*)&yx[obase + 16 * jt + 4 * g] = ac[jt];
                }
            }
        }
    }
    if (l < 16)
        Ls[((gb * 16 + l) * 2 + dir) * 64 + chunk] = L;
}

// ========== dots+gold: 256 blocks (batch) x 256 thr (4 waves) =============
// diff_part[b] = log_z_b - gold_b.  (R16-verified)
__global__ __launch_bounds__(256) void crf_dotsgold_kernel(
    const float* __restrict__ emit, const float* __restrict__ yx,
    const int* __restrict__ Ls, const float* __restrict__ Tm,
    const int* __restrict__ labels, const int* __restrict__ startp,
    float* __restrict__ diff_part)
{
    const int b   = blockIdx.x;
    const int tid = threadIdx.x;
    const int w   = tid >> 6;
    const int l   = tid & 63;
    __shared__ int lab[512];
    __shared__ float rg[4], rd[4];

    lab[tid]       = labels[b * 512 + tid];
    lab[tid + 256] = labels[b * 512 + tid + 256];
    __syncthreads();

    // ---- gold partial (thread handles t = tid, t = tid+256) ----
    float s = 0.f;
    {
        int y0 = lab[tid];
        int p0 = (tid == 0) ? startp[0] : lab[tid - 1];
        s += emit[((size_t)tid * 256 + b) * 128 + y0] + Tm[p0 * 128 + y0];
        int t1 = tid + 256;
        int y1 = lab[t1];
        int p1 = lab[t1 - 1];
        s += emit[((size_t)t1 * 256 + b) * 128 + y1] + Tm[p1 * 128 + y1];
    }
#pragma unroll
    for (int off = 1; off < 64; off <<= 1) s += __shfl_xor(s, off);
    if (l == 0) rg[w] = s;

    // ---- dots terms (c = w, w+4, ...) ----
    const float* yb  = yx + (size_t)(b * 2) * 64 * 128;        // [0][c][j]
    const float* xb  = yb + 64 * 128;                          // [1][c][j]
    const int*   Lyb = Ls + b * 2 * 64;                        // [0][c]

    float acc = 0.f;
#pragma unroll 1
    for (int c = w; c <= 64; c += 4) {
        float term;
        if (c == 64) {
            const float* yp = yb + 63 * 128;
            float s2 = yp[l] + yp[64 + l];
#pragma unroll
            for (int off = 1; off < 64; off <<= 1) s2 += __shfl_xor(s2, off);
            term = __log2f(s2) + (float)Lyb[63];
        } else {
            float pa, pb;
            if (c == 0) {
                pa = __builtin_amdgcn_exp2f(emit[b * 128 + l] * LOG2E);
                pb = __builtin_amdgcn_exp2f(emit[b * 128 + 64 + l] * LOG2E);
            } else {
                const float* yp = yb + (c - 1) * 128;
                pa = yp[l]; pb = yp[64 + l];
            }
            const float* xp = xb + c * 128;
            float xa = xp[l], xb2 = xp[64 + l];
            float sp = pa * xa + pb * xb2;
            float tp = xa + xb2;
#pragma unroll
            for (int off = 1; off < 64; off <<= 1) {
                sp += __shfl_xor(sp, off);
                tp += __shfl_xor(tp, off);
            }
            term = __log2f(sp) - __log2f(tp)
                 + (c ? (float)Lyb[c - 1] : 0.f);
        }
        acc += term;
    }
    if (l == 0) rd[w] = acc;
    __syncthreads();
    if (tid == 0) {
        float lz   = ((rd[0] + rd[1]) + (rd[2] + rd[3])) * LN2F;
        float gold = (rg[0] + rg[1]) + (rg[2] + rg[3]);
        diff_part[b] = lz - gold;
    }
}

// final (fast path): sum 256 diffs.
__global__ __launch_bounds__(256) void crf_sum_kernel(
    const float* __restrict__ diff_part, float* __restrict__ out)
{
    const int tid = threadIdx.x;
    __shared__ float r[4];
    float v = diff_part[tid];
#pragma unroll
    for (int off = 1; off < 64; off <<= 1) v += __shfl_xor(v, off);
    if ((tid & 63) == 0) r[tid >> 6] = v;
    __syncthreads();
    if (tid == 0) out[0] = (r[0] + r[1]) + (r[2] + r[3]);
}

// ================= bf16 fallback full scan (R7, proven) =================
#define MFMAB(Aop, Bop, Cop) \
    __builtin_amdgcn_mfma_f32_16x16x32_bf16( \
        __builtin_bit_cast(bf16x8, Aop), __builtin_bit_cast(bf16x8, Bop), Cop, 0, 0, 0)

#define STEPB(SLOT, TPF, DOPF, RN, LAST) do {                                 \
    f32x4 ac[8];                                                              \
    _Pragma("unroll") for (int jt = 0; jt < 8; ++jt)                          \
        ac[jt] = MFMAB(Afr[0][jt], Bf[0], zero4);                             \
    _Pragma("unroll") for (int ch = 1; ch < 4; ++ch)                          \
        _Pragma("unroll") for (int jt = 0; jt < 8; ++jt)                      \
            ac[jt] = MFMAB(Afr[ch][jt], Bf[ch], ac[jt]);                      \
    float xv[8][4];                                                           \
    _Pragma("unroll") for (int jt = 0; jt < 8; ++jt) {                        \
        float4 xw = xbf[SLOT][jt];                                            \
        xv[jt][0] = __builtin_amdgcn_exp2f(xw.x * LOG2E);                     \
        xv[jt][1] = __builtin_amdgcn_exp2f(xw.y * LOG2E);                     \
        xv[jt][2] = __builtin_amdgcn_exp2f(xw.z * LOG2E);                     \
        xv[jt][3] = __builtin_amdgcn_exp2f(xw.w * LOG2E);                     \
    }                                                                         \
    if (DOPF) {                                                               \
        int tp = (TPF); if (tp > 511) tp = 511;                               \
        _Pragma("unroll") for (int jt = 0; jt < 8; ++jt)                      \
            xbf[SLOT][jt] = emf4[8192 * tp + lb + 4 * jt];                    \
    }                                                                         \
    float vv[8][4];                                                           \
    _Pragma("unroll") for (int jt = 0; jt < 8; ++jt)                          \
        _Pragma("unroll") for (int r = 0; r < 4; ++r)                         \
            vv[jt][r] = ac[jt][r] * xv[jt][r];                                \
    if (RN) {                                                                 \
        float mx = vv[0][0];                                                  \
        _Pragma("unroll") for (int jt = 0; jt < 8; ++jt)                      \
            _Pragma("unroll") for (int r = 0; r < 4; ++r)                     \
                mx = fmaxf(mx, vv[jt][r]);                                    \
        mx = fmaxf(mx, __shfl_xor(mx, 16));                                   \
        mx = fmaxf(mx, __shfl_xor(mx, 32));                                   \
        int Ee = (__float_as_int(mx) >> 23) & 0xFF;                           \
        if (Ee > 254) Ee = 254;                                               \
        ls2 += Ee - 127;                                                      \
        float scl = __int_as_float((254 - Ee) << 23);                         \
        _Pragma("unroll") for (int jt = 0; jt < 8; ++jt)                      \
            _Pragma("unroll") for (int r = 0; r < 4; ++r)                     \
                vv[jt][r] *= scl;                                             \
    }                                                                         \
    if (LAST) {                                                               \
        fin = 0.f;                                                            \
        _Pragma("unroll") for (int jt = 0; jt < 8; ++jt)                      \
            fin += (vv[jt][0] + vv[jt][1]) + (vv[jt][2] + vv[jt][3]);         \
    } else {                                                                  \
        _Pragma("unroll") for (int ch = 0; ch < 4; ++ch) {                    \
            Bf[ch][0] = packbf2(vv[2*ch][0],     vv[2*ch][1]);                \
            Bf[ch][1] = packbf2(vv[2*ch][2],     vv[2*ch][3]);                \
            Bf[ch][2] = packbf2(vv[2*ch + 1][0], vv[2*ch + 1][1]);            \
            Bf[ch][3] = packbf2(vv[2*ch + 1][2], vv[2*ch + 1][3]);            \
        }                                                                     \
    }                                                                         \
} while (0)

__global__ __launch_bounds__(64, 1) void crf_scan_bf16_kernel(
    const float* __restrict__ emit,
    const float* __restrict__ Tm,
    float* __restrict__ scan_part)
{
    const int gb = blockIdx.x;
    const int l  = threadIdx.x;
    const int b  = l & 15;
    const int g  = l >> 4;
    const int bg = gb * 16 + b;
    const int lb = 32 * bg + g;

    const float4* emf4 = (const float4*)emit;
    const f32x4 zero4 = {0.f, 0.f, 0.f, 0.f};

    u32x4 Afr[4][8];
#pragma unroll
    for (int ch = 0; ch < 4; ++ch)
#pragma unroll
        for (int p = 0; p < 4; ++p) {
            const int e0 = 2 * p, e1 = 2 * p + 1;
            const int jp0 = 32 * ch + 16 * (e0 >> 2) + 4 * g + (e0 & 3);
            const int jp1 = 32 * ch + 16 * (e1 >> 2) + 4 * g + (e1 & 3);
#pragma unroll
            for (int jt = 0; jt < 8; ++jt) {
                float a0 = __builtin_amdgcn_exp2f(Tm[jp0 * 128 + 16 * jt + b] * LOG2E);
                float a1 = __builtin_amdgcn_exp2f(Tm[jp1 * 128 + 16 * jt + b] * LOG2E);
                Afr[ch][jt][p] = packbf2(a0, a1);
            }
        }

    u32x4 Bf[4];
    {
        float x0[8][4];
#pragma unroll
        for (int jt = 0; jt < 8; ++jt) {
            float4 e = emf4[lb + 4 * jt];
            x0[jt][0] = __builtin_amdgcn_exp2f(e.x * LOG2E);
            x0[jt][1] = __builtin_amdgcn_exp2f(e.y * LOG2E);
            x0[jt][2] = __builtin_amdgcn_exp2f(e.z * LOG2E);
            x0[jt][3] = __builtin_amdgcn_exp2f(e.w * LOG2E);
        }
#pragma unroll
        for (int ch = 0; ch < 4; ++ch) {
            Bf[ch][0] = packbf2(x0[2 * ch][0],     x0[2 * ch][1]);
            Bf[ch][1] = packbf2(x0[2 * ch][2],     x0[2 * ch][3]);
            Bf[ch][2] = packbf2(x0[2 * ch + 1][0], x0[2 * ch + 1][1]);
            Bf[ch][3] = packbf2(x0[2 * ch + 1][2], x0[2 * ch + 1][3]);
        }
    }

    float4 xbf[4][8];
#pragma unroll
    for (int k = 0; k < 4; ++k)
#pragma unroll
        for (int jt = 0; jt < 8; ++jt)
            xbf[k][jt] = emf4[8192 * (1 + k) + lb + 4 * jt];

    int ls2 = 0;
    float fin = 0.f;

#pragma unroll 1
    for (int grp = 0; grp < 63; ++grp) {
        const int t0 = 1 + 8 * grp;
        STEPB(0, t0 + 4,  1, 0, 0);
        STEPB(1, t0 + 5,  1, 0, 0);
        STEPB(2, t0 + 6,  1, 0, 0);
        STEPB(3, t0 + 7,  1, 0, 0);
        STEPB(0, t0 + 8,  1, 0, 0);
        STEPB(1, t0 + 9,  1, 0, 0);
        STEPB(2, t0 + 10, 1, 0, 0);
        STEPB(3, t0 + 11, 1, 1, 0);
    }
    STEPB(0, 509, 1, 0, 0);
    STEPB(1, 510, 1, 0, 0);
    STEPB(2, 511, 1, 0, 0);
    STEPB(3, 0,   0, 0, 0);
    STEPB(0, 0,   0, 0, 0);
    STEPB(1, 0,   0, 0, 0);
    STEPB(2, 0,   0, 0, 1);

    fin += __shfl_xor(fin, 16);
    fin += __shfl_xor(fin, 32);
    if (l < 16)
        scan_part[gb * 16 + l] = ((float)ls2 + __log2f(fin)) * LN2F;
}

// ================= gold + final (fallback path) =================
__global__ __launch_bounds__(256) void crf_gold_kernel(
    const float* __restrict__ emit, const float* __restrict__ Tm,
    const int* __restrict__ labels, const int* __restrict__ startp,
    float* __restrict__ gold_part)
{
    const int b = blockIdx.x, tid = threadIdx.x;
    __shared__ int lab[512];
    __shared__ float r[4];
    lab[tid]       = labels[b * 512 + tid];
    lab[tid + 256] = labels[b * 512 + tid + 256];
    __syncthreads();
    float s = 0.f;
    {
        int y0 = lab[tid];
        int p0 = (tid == 0) ? startp[0] : lab[tid - 1];
        s += emit[((size_t)tid * 256 + b) * 128 + y0] + Tm[p0 * 128 + y0];
        int t1 = tid + 256;
        int y1 = lab[t1];
        int p1 = lab[t1 - 1];
        s += emit[((size_t)t1 * 256 + b) * 128 + y1] + Tm[p1 * 128 + y1];
    }
#pragma unroll
    for (int off = 1; off < 64; off <<= 1) s += __shfl_xor(s, off);
    if ((tid & 63) == 0) r[tid >> 6] = s;
    __syncthreads();
    if (tid == 0) gold_part[b] = (r[0] + r[1]) + (r[2] + r[3]);
}

__global__ __launch_bounds__(256) void crf_final_kernel(
    const float* __restrict__ scan_part, const float* __restrict__ gold_part,
    float* __restrict__ out)
{
    const int tid = threadIdx.x;
    __shared__ float r[4];
    float v = scan_part[tid] - gold_part[tid];
#pragma unroll
    for (int off = 1; off < 64; off <<= 1) v += __shfl_xor(v, off);
    if ((tid & 63) == 0) r[tid >> 6] = v;
    __syncthreads();
    if (tid == 0) out[0] = (r[0] + r[1]) + (r[2] + r[3]);
}

extern "C" void kernel_launch(void* const* d_in, const int* in_sizes, int n_in,
                              void* d_out, int out_size, void* d_ws, size_t ws_size,
                              hipStream_t stream) {
    const float* emit   = (const float*)d_in[0];
    const float* Tm     = (const float*)d_in[1];
    const int*   labels = (const int*)d_in[2];
    const int*   startp = (const int*)d_in[3];

    const size_t af_bytes = (size_t)2 * 8 * 64 * 32;          // 32,768
    const size_t yx_bytes = (size_t)256 * 2 * 64 * 128 * 4;   // 16,777,216
    const size_t Ls_bytes = (size_t)256 * 2 * 64 * 4;         // 131,072

    if (ws_size >= af_bytes + yx_bytes + Ls_bytes + 4096) {
        int*   Afrbuf    = (int*)d_ws;
        float* yx        = (float*)((char*)d_ws + af_bytes);
        int*   Ls        = (int*)((char*)d_ws + af_bytes + yx_bytes);
        float* diff_part = (float*)((char*)d_ws + af_bytes + yx_bytes + Ls_bytes);
        crf_setup_kernel   <<<16,   64, 0, stream>>>(Tm, Afrbuf);
        crf_chunk_kernel   <<<1024, 256, 0, stream>>>(emit, Afrbuf, yx, Ls);
        crf_dotsgold_kernel<<<256,  256, 0, stream>>>(emit, yx, Ls, Tm, labels,
                                                      startp, diff_part);
        crf_sum_kernel     <<<1,    256, 0, stream>>>(diff_part, (float*)d_out);
    } else {
        float* scan_part = (float*)d_ws;
        float* gold_part = scan_part + 256;
        crf_scan_bf16_kernel<<<16, 64, 0, stream>>>(emit, Tm, scan_part);
        crf_gold_kernel<<<256, 256, 0, stream>>>(emit, Tm, labels, startp, gold_part);
        crf_final_kernel<<<1, 256, 0, stream>>>(scan_part, gold_part, (float*)d_out);
    }
}